// Round 1
// baseline (26258.420 us; speedup 1.0000x reference)
//
#include <hip/hip_runtime.h>

// QINCoStep fused kernel — round 1: fp32 VALU correctness baseline.
// D=128, K=256, HID=256, NBLK=2, N=4096.
// Outputs (flat f32): codes[N] | x_hat_new[N*D] | r[N*D] | c_sel[N*D]

#define QD    128
#define QK    256
#define QHID  256
#define QNBLK 2
#define QN    4096

// ---------------------------------------------------------------------------
// Kernel 0: c_part[k][d] = sum_e cb[k,e] * Wp[d, D+e] + bp[d]   (256x128)
// ---------------------------------------------------------------------------
__global__ __launch_bounds__(QD) void qinco_cpart(const float* __restrict__ cb,
                                                  const float* __restrict__ Wp,
                                                  const float* __restrict__ bp,
                                                  float* __restrict__ cpart) {
    const int k = blockIdx.x;
    const int d = threadIdx.x;
    __shared__ float row[QD];
    row[d] = cb[k * QD + d];
    __syncthreads();
    float acc = bp[d];
    const float* wrow = Wp + d * (2 * QD) + QD;  // Wp[d, D:]
    #pragma unroll 8
    for (int e = 0; e < QD; ++e) acc = fmaf(row[e], wrow[e], acc);
    cpart[k * QD + d] = acc;
}

// ---------------------------------------------------------------------------
// Main kernel: one block per n; thread k owns code row k (C[128] in regs).
// ---------------------------------------------------------------------------
__global__ __launch_bounds__(QK, 1) void qinco_main(
    const float* __restrict__ x, const float* __restrict__ xh,
    const float* __restrict__ Wp,
    const float* __restrict__ W1, const float* __restrict__ b1,
    const float* __restrict__ W2, const float* __restrict__ b2,
    const float* __restrict__ cpart, float* __restrict__ out) {
    const int n = blockIdx.x;
    const int k = threadIdx.x;

    __shared__ float xh_s[QD];
    __shared__ float xp_s[QD];
    __shared__ float r_s[QD];
    __shared__ float red_d[QK];
    __shared__ int   red_i[QK];

    // Stage x_hat row, residual r = x - x_hat.
    if (k < QD) {
        float xv  = x[(size_t)n * QD + k];
        float xhv = xh[(size_t)n * QD + k];
        xh_s[k] = xhv;
        r_s[k]  = xv - xhv;
    }
    __syncthreads();

    // x_part[d] = sum_e x_hat[n,e] * Wp[d, e]
    if (k < QD) {
        float acc = 0.f;
        const float* wrow = Wp + k * (2 * QD);  // Wp[k, :D]
        #pragma unroll 8
        for (int e = 0; e < QD; ++e) acc = fmaf(xh_s[e], wrow[e], acc);
        xp_s[k] = acc;
    }
    __syncthreads();

    // C row for this (n, k): statically-indexed register array.
    float C[QD];
    float Cn[QD];
    {
        const float* cp = cpart + k * QD;
        #pragma unroll
        for (int d = 0; d < QD; ++d) C[d] = xp_s[d] + cp[d];
    }

    // Residual blocks: h = relu(C @ W1^T + b1); C = C + h @ W2^T + b2.
    // Processed in h-chunks of 8 so only 8 h-values are live at a time.
    #pragma unroll 1
    for (int b = 0; b < QNBLK; ++b) {
        const float* w1  = W1 + b * QHID * QD;   // [HID][D]
        const float* w2  = W2 + b * QD * QHID;   // [D][HID]
        const float* bb1 = b1 + b * QHID;
        const float* bb2 = b2 + b * QD;

        #pragma unroll
        for (int d = 0; d < QD; ++d) Cn[d] = 0.f;

        #pragma unroll 1
        for (int hc = 0; hc < QHID / 8; ++hc) {
            float s[8];
            #pragma unroll
            for (int j = 0; j < 8; ++j) s[j] = bb1[hc * 8 + j];

            // matmul1: s[j] += sum_d C[d] * W1[hc*8+j, d]   (weights wave-uniform -> SGPR)
            const float* w1c = w1 + (hc * 8) * QD;
            #pragma unroll
            for (int d = 0; d < QD; ++d) {
                float cv = C[d];
                #pragma unroll
                for (int j = 0; j < 8; ++j) s[j] = fmaf(cv, w1c[j * QD + d], s[j]);
            }
            #pragma unroll
            for (int j = 0; j < 8; ++j) s[j] = fmaxf(s[j], 0.f);

            // matmul2: Cn[d] += sum_j s[j] * W2[d, hc*8+j]
            const float* w2c = w2 + hc * 8;
            #pragma unroll
            for (int d = 0; d < QD; ++d) {
                float acc = Cn[d];
                #pragma unroll
                for (int j = 0; j < 8; ++j) acc = fmaf(s[j], w2c[d * QHID + j], acc);
                Cn[d] = acc;
            }
        }

        #pragma unroll
        for (int d = 0; d < QD; ++d) C[d] += Cn[d] + bb2[d];
    }

    // Squared distance to r.
    float dist = 0.f;
    #pragma unroll
    for (int d = 0; d < QD; ++d) {
        float t = r_s[d] - C[d];
        dist = fmaf(t, t, dist);
    }
    red_d[k] = dist;
    red_i[k] = k;
    __syncthreads();

    // Argmin with first-index tie-break (matches jnp.argmin).
    for (int off = QK / 2; off > 0; off >>= 1) {
        if (k < off) {
            float d2 = red_d[k + off]; int i2 = red_i[k + off];
            float d1 = red_d[k];       int i1 = red_i[k];
            if (d2 < d1 || (d2 == d1 && i2 < i1)) { red_d[k] = d2; red_i[k] = i2; }
        }
        __syncthreads();
    }
    const int code = red_i[0];

    // Winner publishes its C row (reuse xp_s).
    if (k == code) {
        #pragma unroll
        for (int d = 0; d < QD; ++d) xp_s[d] = C[d];
    }
    __syncthreads();

    // Outputs: codes | x_hat_new | r | c_sel  (all as f32)
    if (k == 0) out[n] = (float)code;
    if (k < QD) {
        float cs = xp_s[k];
        out[QN + (size_t)n * QD + k]                = xh_s[k] + cs;  // x_hat_new
        out[QN + (size_t)QN * QD + (size_t)n * QD + k]     = r_s[k]; // r
        out[QN + 2 * (size_t)QN * QD + (size_t)n * QD + k] = cs;     // c_sel
    }
}

// ---------------------------------------------------------------------------
extern "C" void kernel_launch(void* const* d_in, const int* in_sizes, int n_in,
                              void* d_out, int out_size, void* d_ws, size_t ws_size,
                              hipStream_t stream) {
    const float* x   = (const float*)d_in[0];
    const float* xh  = (const float*)d_in[1];
    const float* cb  = (const float*)d_in[2];
    const float* Wp  = (const float*)d_in[3];
    const float* bp  = (const float*)d_in[4];
    const float* W1  = (const float*)d_in[5];
    const float* b1  = (const float*)d_in[6];
    const float* W2  = (const float*)d_in[7];
    const float* b2  = (const float*)d_in[8];
    float* out = (float*)d_out;

    float* cpart = (float*)d_ws;  // K*D f32 = 128 KiB

    qinco_cpart<<<QK, QD, 0, stream>>>(cb, Wp, bp, cpart);
    qinco_main<<<QN, QK, 0, stream>>>(x, xh, Wp, W1, b1, W2, b2, cpart, out);
}

// Round 3
// 917.641 us; speedup vs baseline: 28.6151x; 28.6151x over previous
//
#include <hip/hip_runtime.h>

// QINCoStep fused kernel — round 3: MFMA f16x3, fixed ws overflow, 36KB static LDS.
// D=128, K=256, HID=256, NBLK=2, N=4096.
// Outputs (flat f32): codes[N] | x_hat_new[N*D] | r[N*D] | c_sel[N*D]

#define QD    128
#define QK    256
#define QHID  256
#define QNBLK 2
#define QN    4096

typedef _Float16 f16;
typedef _Float16 f16x8 __attribute__((ext_vector_type(8)));
typedef float    f32x4 __attribute__((ext_vector_type(4)));

// ---- workspace layout (bytes) ----  [round-2 bug: these were half-sized]
#define WS_CPART 0          // f32 [256*128]                  = 131072 B
#define WS_W1H   131072     // f16 [128 cids * 64 * 8] = 65536 elems = 131072 B
#define WS_W1L   262144
#define WS_W2H   393216
#define WS_W2L   524288     // end: 655360 (640 KiB)

static __device__ __forceinline__ f32x4 MF(f16x8 a, f16x8 b, f32x4 c) {
    return __builtin_amdgcn_mfma_f32_16x16x32_f16(a, b, c, 0, 0, 0);
}

static __device__ __forceinline__ unsigned pack_hl(float v) {
    f16 hi = (f16)v;
    f16 lo = (f16)(v - (float)hi);
    return (unsigned)__builtin_bit_cast(unsigned short, hi)
         | ((unsigned)__builtin_bit_cast(unsigned short, lo) << 16);
}

static __device__ __forceinline__ void unpack_frag(uint4 v0, uint4 v1,
                                                   f16x8* hi, f16x8* lo) {
    union { unsigned u[4]; f16x8 v; } ch, cl;
    ch.u[0] = (v0.x & 0xffffu) | (v0.y << 16);
    cl.u[0] = (v0.x >> 16)     | (v0.y & 0xffff0000u);
    ch.u[1] = (v0.z & 0xffffu) | (v0.w << 16);
    cl.u[1] = (v0.z >> 16)     | (v0.w & 0xffff0000u);
    ch.u[2] = (v1.x & 0xffffu) | (v1.y << 16);
    cl.u[2] = (v1.x >> 16)     | (v1.y & 0xffff0000u);
    ch.u[3] = (v1.z & 0xffffu) | (v1.w << 16);
    cl.u[3] = (v1.z >> 16)     | (v1.w & 0xffff0000u);
    *hi = ch.v; *lo = cl.v;
}

// ---------------------------------------------------------------------------
// Prep: cpart (f32) + weights split hi/lo f16 in exact B-fragment lane order.
// B-frag: lane l elem j = B[k = kslot(l>>4, j)][n = l&15]; we pack logical
// k = base + (l>>4)*8 + j into slot (l>>4, j) for BOTH A and B, so any HW
// k-permutation cancels.
// ---------------------------------------------------------------------------
__global__ __launch_bounds__(128) void qinco_prep(
    const float* __restrict__ cb, const float* __restrict__ Wp,
    const float* __restrict__ bp, const float* __restrict__ W1,
    const float* __restrict__ W2, char* __restrict__ ws) {
    const int blk = blockIdx.x;
    const int t = threadIdx.x;
    __shared__ float row[QD];

    if (blk < 256) {
        float* cpart = (float*)(ws + WS_CPART);
        row[t] = cb[blk * QD + t];
        __syncthreads();
        float acc = bp[t];
        const float* wr = Wp + (size_t)t * (2 * QD) + QD;
        #pragma unroll 8
        for (int e = 0; e < QD; ++e) acc = fmaf(row[e], wr[e], acc);
        cpart[blk * QD + t] = acc;
    } else if (blk < 384) {
        if (t < 64) {
            const int cid = blk - 256;            // b*64 + hc16*4 + kk
            const int b = cid >> 6, hc16 = (cid >> 2) & 15, kk = cid & 3;
            const int ln = t & 15, lg = t >> 4;
            f16* w1h = (f16*)(ws + WS_W1H);
            f16* w1l = (f16*)(ws + WS_W1L);
            #pragma unroll
            for (int j = 0; j < 8; ++j) {
                float w = W1[((size_t)b * QHID + hc16 * 16 + ln) * QD + kk * 32 + lg * 8 + j];
                f16 hi = (f16)w;
                size_t idx = ((size_t)cid * 64 + t) * 8 + j;
                w1h[idx] = hi;
                w1l[idx] = (f16)(w - (float)hi);
            }
        }
    } else {
        if (t < 64) {
            const int cid = blk - 384;            // b*64 + d16*8 + hc
            const int b = cid >> 6, d16 = (cid >> 3) & 7, hc = cid & 7;
            const int ln = t & 15, lg = t >> 4;
            f16* w2h = (f16*)(ws + WS_W2H);
            f16* w2l = (f16*)(ws + WS_W2L);
            #pragma unroll
            for (int j = 0; j < 8; ++j) {
                float w = W2[((size_t)b * QD + d16 * 16 + ln) * QHID + hc * 32 + lg * 8 + j];
                f16 hi = (f16)w;
                size_t idx = ((size_t)cid * 64 + t) * 8 + j;
                w2h[idx] = hi;
                w2l[idx] = (f16)(w - (float)hi);
            }
        }
    }
}

// ---------------------------------------------------------------------------
// Main: one block per n; 8 waves x 32 code-rows. No __syncthreads in the
// GEMM loop (all staging is wave-private through a 4KB packed-u32 tile).
// ---------------------------------------------------------------------------
__global__ __launch_bounds__(512, 2) void qinco_main(
    const float* __restrict__ x, const float* __restrict__ xh,
    const float* __restrict__ Wp,
    const float* __restrict__ b1g, const float* __restrict__ b2g,
    const char* __restrict__ ws, float* __restrict__ out) {

    __shared__ unsigned stage[8][1024];  // per-wave [32 rows][32 u32], 32 KiB
    __shared__ float red_d[QK];
    __shared__ int   red_i[QK];
    __shared__ float xp_s[QD], xh_s[QD], r_s[QD], csel[QD];

    const int n = blockIdx.x;
    const int t = threadIdx.x;
    const int w = t >> 6;
    const int l = t & 63;
    const int ln = l & 15, lg = l >> 4;
    const int baserow = w * 32;

    const float* cpart = (const float*)(ws + WS_CPART);
    const f16* w1h = (const f16*)(ws + WS_W1H);
    const f16* w1l = (const f16*)(ws + WS_W1L);
    const f16* w2h = (const f16*)(ws + WS_W2H);
    const f16* w2l = (const f16*)(ws + WS_W2L);

    unsigned* stW = stage[w];

    // ---- stage xh, compute x_part ----
    if (t < QD) xh_s[t] = xh[(size_t)n * QD + t];
    __syncthreads();
    if (t < QD) {
        const float4* wr = (const float4*)(Wp + (size_t)t * (2 * QD));
        const float4* xv = (const float4*)xh_s;
        float acc = 0.f;
        #pragma unroll
        for (int j = 0; j < QD / 4; ++j) {
            float4 a = wr[j], bv = xv[j];
            acc = fmaf(a.x, bv.x, acc);
            acc = fmaf(a.y, bv.y, acc);
            acc = fmaf(a.z, bv.z, acc);
            acc = fmaf(a.w, bv.w, acc);
        }
        xp_s[t] = acc;
    }
    __syncthreads();

    // ---- init C: Cacc[i][d] lane l reg q = C[baserow+i*16+lg*4+q][d*16+ln] ----
    f32x4 Cacc[2][8];
    #pragma unroll
    for (int i = 0; i < 2; ++i)
        #pragma unroll
        for (int d = 0; d < 8; ++d) {
            float xpv = xp_s[d * 16 + ln];
            #pragma unroll
            for (int q = 0; q < 4; ++q)
                Cacc[i][d][q] = xpv +
                    cpart[(size_t)(baserow + i * 16 + lg * 4 + q) * QD + d * 16 + ln];
        }

    // ---- residual blocks ----
    #pragma unroll 1
    for (int b = 0; b < QNBLK; ++b) {
        // split C -> A1 fragments, one 32-col chunk at a time through stage
        f16x8 a1hi[2][4], a1lo[2][4];
        #pragma unroll
        for (int kk = 0; kk < 4; ++kk) {
            #pragma unroll
            for (int i = 0; i < 2; ++i)
                #pragma unroll
                for (int dl = 0; dl < 2; ++dl) {
                    const int d = kk * 2 + dl;
                    #pragma unroll
                    for (int q = 0; q < 4; ++q) {
                        int row = i * 16 + lg * 4 + q;
                        int col = dl * 16 + ln;
                        stW[row * 32 + (col ^ ((row & 7) << 2))] = pack_hl(Cacc[i][d][q]);
                    }
                }
            #pragma unroll
            for (int i = 0; i < 2; ++i) {
                int row = i * 16 + ln;
                int sw = (row & 7) << 2;
                const unsigned* base = stW + row * 32;
                uint4 v0 = *(const uint4*)(base + ((lg * 8) ^ sw));
                uint4 v1 = *(const uint4*)(base + ((lg * 8 + 4) ^ sw));
                unpack_frag(v0, v1, &a1hi[i][kk], &a1lo[i][kk]);
            }
        }

        const float* b1row = b1g + (size_t)b * QHID;
        const float* b2row = b2g + (size_t)b * QD;

        #pragma unroll 1
        for (int hc = 0; hc < 8; ++hc) {
            // H init with b1 broadcast (bias per output column = ln)
            f32x4 H[2][2];
            {
                float bv0 = b1row[hc * 32 + ln];
                float bv1 = b1row[hc * 32 + 16 + ln];
                #pragma unroll
                for (int i = 0; i < 2; ++i) {
                    H[i][0] = (f32x4){bv0, bv0, bv0, bv0};
                    H[i][1] = (f32x4){bv1, bv1, bv1, bv1};
                }
            }
            // GEMM1: H += C @ W1^T  (f16x3: hi*hi + lo*hi + hi*lo)
            #pragma unroll
            for (int kk = 0; kk < 4; ++kk) {
                const size_t o0 = ((size_t)(b * 64 + hc * 8 + kk) * 64 + l) * 8;
                const size_t o1 = ((size_t)(b * 64 + hc * 8 + 4 + kk) * 64 + l) * 8;
                f16x8 bh0 = *(const f16x8*)(w1h + o0);
                f16x8 bh1 = *(const f16x8*)(w1h + o1);
                f16x8 bl0 = *(const f16x8*)(w1l + o0);
                f16x8 bl1 = *(const f16x8*)(w1l + o1);
                H[0][0] = MF(a1hi[0][kk], bh0, H[0][0]);
                H[1][0] = MF(a1hi[1][kk], bh0, H[1][0]);
                H[0][1] = MF(a1hi[0][kk], bh1, H[0][1]);
                H[1][1] = MF(a1hi[1][kk], bh1, H[1][1]);
                H[0][0] = MF(a1lo[0][kk], bh0, H[0][0]);
                H[1][0] = MF(a1lo[1][kk], bh0, H[1][0]);
                H[0][1] = MF(a1lo[0][kk], bh1, H[0][1]);
                H[1][1] = MF(a1lo[1][kk], bh1, H[1][1]);
                H[0][0] = MF(a1hi[0][kk], bl0, H[0][0]);
                H[1][0] = MF(a1hi[1][kk], bl0, H[1][0]);
                H[0][1] = MF(a1hi[0][kk], bl1, H[0][1]);
                H[1][1] = MF(a1hi[1][kk], bl1, H[1][1]);
            }
            // relu + split h -> stage (packed u32)
            #pragma unroll
            for (int i = 0; i < 2; ++i)
                #pragma unroll
                for (int cc = 0; cc < 2; ++cc)
                    #pragma unroll
                    for (int q = 0; q < 4; ++q) {
                        float v = fmaxf(H[i][cc][q], 0.f);
                        int row = i * 16 + lg * 4 + q;
                        int col = cc * 16 + ln;
                        stW[row * 32 + (col ^ ((row & 7) << 2))] = pack_hl(v);
                    }
            // load A2 fragments
            f16x8 a2hi[2], a2lo[2];
            #pragma unroll
            for (int i = 0; i < 2; ++i) {
                int row = i * 16 + ln;
                int sw = (row & 7) << 2;
                const unsigned* base = stW + row * 32;
                uint4 v0 = *(const uint4*)(base + ((lg * 8) ^ sw));
                uint4 v1 = *(const uint4*)(base + ((lg * 8 + 4) ^ sw));
                unpack_frag(v0, v1, &a2hi[i], &a2lo[i]);
            }
            // GEMM2: C += h @ W2^T  (f16x3)
            #pragma unroll
            for (int d = 0; d < 8; ++d) {
                const size_t o2 = ((size_t)(b * 64 + d * 8 + hc) * 64 + l) * 8;
                f16x8 b2h = *(const f16x8*)(w2h + o2);
                f16x8 b2l = *(const f16x8*)(w2l + o2);
                Cacc[0][d] = MF(a2hi[0], b2h, Cacc[0][d]);
                Cacc[1][d] = MF(a2hi[1], b2h, Cacc[1][d]);
                Cacc[0][d] = MF(a2hi[0], b2l, Cacc[0][d]);
                Cacc[1][d] = MF(a2hi[1], b2l, Cacc[1][d]);
                Cacc[0][d] = MF(a2lo[0], b2h, Cacc[0][d]);
                Cacc[1][d] = MF(a2lo[1], b2h, Cacc[1][d]);
            }
        } // hc

        // add b2
        #pragma unroll
        for (int d = 0; d < 8; ++d) {
            float bv = b2row[d * 16 + ln];
            #pragma unroll
            for (int i = 0; i < 2; ++i)
                #pragma unroll
                for (int q = 0; q < 4; ++q)
                    Cacc[i][d][q] += bv;
        }
    } // b

    // ---- distances & argmin ----
    if (t < QD) {
        float xv  = x[(size_t)n * QD + t];
        float xhv = xh[(size_t)n * QD + t];
        r_s[t] = xv - xhv;
    }
    __syncthreads();

    float rv[8];
    #pragma unroll
    for (int d = 0; d < 8; ++d) rv[d] = r_s[d * 16 + ln];

    #pragma unroll
    for (int i = 0; i < 2; ++i)
        #pragma unroll
        for (int q = 0; q < 4; ++q) {
            float pd = 0.f;
            #pragma unroll
            for (int d = 0; d < 8; ++d) {
                float tt = rv[d] - Cacc[i][d][q];
                pd = fmaf(tt, tt, pd);
            }
            pd += __shfl_xor(pd, 1);
            pd += __shfl_xor(pd, 2);
            pd += __shfl_xor(pd, 4);
            pd += __shfl_xor(pd, 8);
            if (ln == 0) {
                int row = baserow + i * 16 + lg * 4 + q;
                red_d[row] = pd;
                red_i[row] = row;
            }
        }
    __syncthreads();

    for (int off = 128; off > 0; off >>= 1) {
        if (t < off) {
            float d2 = red_d[t + off]; int i2 = red_i[t + off];
            float d1 = red_d[t];       int i1 = red_i[t];
            if (d2 < d1 || (d2 == d1 && i2 < i1)) { red_d[t] = d2; red_i[t] = i2; }
        }
        __syncthreads();
    }
    const int code = red_i[0];

    // winner publishes its C row (static acc indexing via predication)
    if (w == (code >> 5) && lg == ((code >> 2) & 3)) {
        const int ci = (code >> 4) & 1, cq = code & 3;
        #pragma unroll
        for (int i = 0; i < 2; ++i)
            if (i == ci)
                #pragma unroll
                for (int q = 0; q < 4; ++q)
                    if (q == cq)
                        #pragma unroll
                        for (int d = 0; d < 8; ++d)
                            csel[d * 16 + ln] = Cacc[i][d][q];
    }
    __syncthreads();

    // ---- outputs ----
    if (t == 0) out[n] = (float)code;
    if (t < QD) {
        float cs  = csel[t];
        float xhv = xh_s[t];
        out[QN + (size_t)n * QD + t]                       = xhv + cs;   // x_hat_new
        out[QN + (size_t)QN * QD + (size_t)n * QD + t]     = r_s[t];     // r
        out[QN + 2 * (size_t)QN * QD + (size_t)n * QD + t] = cs;         // c_sel
    }
}

// ---------------------------------------------------------------------------
extern "C" void kernel_launch(void* const* d_in, const int* in_sizes, int n_in,
                              void* d_out, int out_size, void* d_ws, size_t ws_size,
                              hipStream_t stream) {
    const float* x   = (const float*)d_in[0];
    const float* xh  = (const float*)d_in[1];
    const float* cb  = (const float*)d_in[2];
    const float* Wp  = (const float*)d_in[3];
    const float* bp  = (const float*)d_in[4];
    const float* W1  = (const float*)d_in[5];
    const float* b1  = (const float*)d_in[6];
    const float* W2  = (const float*)d_in[7];
    const float* b2  = (const float*)d_in[8];
    float* out = (float*)d_out;

    qinco_prep<<<512, 128, 0, stream>>>(cb, Wp, bp, W1, W2, (char*)d_ws);
    qinco_main<<<QN, 512, 0, stream>>>(x, xh, Wp, b1, b2, (const char*)d_ws, out);
}

// Round 4
// 827.445 us; speedup vs baseline: 31.7343x; 1.1090x over previous
//
#include <hip/hip_runtime.h>

// QINCoStep fused kernel — round 4: software-pipelined hc loop, split hi/lo
// LDS planes (no unpack), double-buffered stage, W2 repacked per-hc.
// D=128, K=256, HID=256, NBLK=2, N=4096.
// Outputs (flat f32): codes[N] | x_hat_new[N*D] | r[N*D] | c_sel[N*D]

#define QD    128
#define QK    256
#define QHID  256
#define QNBLK 2
#define QN    4096

typedef _Float16 f16;
typedef _Float16 f16x8 __attribute__((ext_vector_type(8)));
typedef float    f32x4 __attribute__((ext_vector_type(4)));

// ---- workspace layout (bytes) ----
#define WS_CPART 0          // f32 [256*128]                = 131072 B
#define WS_W1H   131072     // f16 [128 cids][64][8]        = 131072 B
#define WS_W1L   262144
#define WS_W2H   393216
#define WS_W2L   524288     // end 655360

// ---- dynamic LDS carve (bytes) ----
#define L_STAGE  0          // f16 [8 waves][2 buf][2 planes][1024] = 65536
#define L_REDD   65536      // f32[256]
#define L_REDI   66560      // i32[256]
#define L_XP     67584      // f32[128]
#define L_XH     68096      // f32[128]
#define L_RS     68608      // f32[128]
#define L_CSEL   69120      // f32[128]
#define L_TOTAL  69632

static __device__ __forceinline__ f32x4 MF(f16x8 a, f16x8 b, f32x4 c) {
    return __builtin_amdgcn_mfma_f32_16x16x32_f16(a, b, c, 0, 0, 0);
}

// ---------------------------------------------------------------------------
// Prep: cpart (f32) + weights split hi/lo f16 in B-fragment lane order.
// W1: cid = b*64 + hc16*4 + kk   (hc16 = 16-wide h tile, kk = 32-wide d chunk)
// W2: cid = b*64 + hc*8 + d16    (hc = 32-wide h chunk, d16 = 16-wide d tile)
// ---------------------------------------------------------------------------
__global__ __launch_bounds__(128) void qinco_prep(
    const float* __restrict__ cb, const float* __restrict__ Wp,
    const float* __restrict__ bp, const float* __restrict__ W1,
    const float* __restrict__ W2, char* __restrict__ ws) {
    const int blk = blockIdx.x;
    const int t = threadIdx.x;
    __shared__ float row[QD];

    if (blk < 256) {
        float* cpart = (float*)(ws + WS_CPART);
        row[t] = cb[blk * QD + t];
        __syncthreads();
        float acc = bp[t];
        const float* wr = Wp + (size_t)t * (2 * QD) + QD;
        #pragma unroll 8
        for (int e = 0; e < QD; ++e) acc = fmaf(row[e], wr[e], acc);
        cpart[blk * QD + t] = acc;
    } else if (blk < 384) {
        if (t < 64) {
            const int cid = blk - 256;            // b*64 + hc16*4 + kk
            const int b = cid >> 6, hc16 = (cid >> 2) & 15, kk = cid & 3;
            const int ln = t & 15, lg = t >> 4;
            f16* w1h = (f16*)(ws + WS_W1H);
            f16* w1l = (f16*)(ws + WS_W1L);
            #pragma unroll
            for (int j = 0; j < 8; ++j) {
                float w = W1[((size_t)b * QHID + hc16 * 16 + ln) * QD + kk * 32 + lg * 8 + j];
                f16 hi = (f16)w;
                size_t idx = ((size_t)cid * 64 + t) * 8 + j;
                w1h[idx] = hi;
                w1l[idx] = (f16)(w - (float)hi);
            }
        }
    } else {
        if (t < 64) {
            const int e = blk - 384;              // b*64 + hc*8 + d16
            const int b = e >> 6, hc = (e >> 3) & 7, d16 = e & 7;
            const int ln = t & 15, lg = t >> 4;
            f16* w2h = (f16*)(ws + WS_W2H);
            f16* w2l = (f16*)(ws + WS_W2L);
            #pragma unroll
            for (int j = 0; j < 8; ++j) {
                float w = W2[((size_t)b * QD + d16 * 16 + ln) * QHID + hc * 32 + lg * 8 + j];
                f16 hi = (f16)w;
                size_t idx = ((size_t)e * 64 + t) * 8 + j;
                w2h[idx] = hi;
                w2l[idx] = (f16)(w - (float)hi);
            }
        }
    }
}

// ---------------------------------------------------------------------------
// Main: one block per n; 8 waves x 32 code rows; pipelined hc loop.
// ---------------------------------------------------------------------------
__global__ __launch_bounds__(512, 2) void qinco_main(
    const float* __restrict__ x, const float* __restrict__ xh,
    const float* __restrict__ Wp,
    const float* __restrict__ b1g, const float* __restrict__ b2g,
    const char* __restrict__ ws, float* __restrict__ out) {

    extern __shared__ char smem[];
    const int n = blockIdx.x;
    const int t = threadIdx.x;
    const int w = t >> 6;
    const int l = t & 63;
    const int ln = l & 15, lg = l >> 4;
    const int baserow = w * 32;

    f16*   stW   = (f16*)(smem + L_STAGE) + (size_t)w * 4096; // 2 bufs x (hi|lo) x 1024
    float* red_d = (float*)(smem + L_REDD);
    int*   red_i = (int*)(smem + L_REDI);
    float* xp_s  = (float*)(smem + L_XP);
    float* xh_s  = (float*)(smem + L_XH);
    float* r_s   = (float*)(smem + L_RS);
    float* csel  = (float*)(smem + L_CSEL);

    const float* cpart = (const float*)(ws + WS_CPART);

    // stage write: logical (row = i*16+lg*4+q, col = cb*16+ln), swizzled
    #define STW(buf, i, cb, q, hv, lv) {                                      \
        int idx_ = ((((i)*16 + lg*4 + (q)) * 32) + ((cb)*16 + ln)) ^ (lg << 4);\
        stW[(buf)*2048 + idx_]        = (hv);                                  \
        stW[(buf)*2048 + 1024 + idx_] = (lv); }

    // stage frag read: row = i*16+ln, cols lg*8..lg*8+7 (A-frag layout)
    #define LDF(buf, i, hi_, lo_) {                                            \
        int idx_ = (((i)*16 + ln) * 32 + lg*8) ^ (((ln >> 2) & 3) << 4);       \
        hi_ = *(const f16x8*)(stW + (buf)*2048 + idx_);                        \
        lo_ = *(const f16x8*)(stW + (buf)*2048 + 1024 + idx_); }

    // split C chunk kk into stage buf
    #define WRC(kk, buf)                                                       \
        _Pragma("unroll") for (int i_ = 0; i_ < 2; ++i_)                       \
        _Pragma("unroll") for (int dl_ = 0; dl_ < 2; ++dl_)                    \
        _Pragma("unroll") for (int q_ = 0; q_ < 4; ++q_) {                     \
            float v_ = Cacc[i_][(kk)*2 + dl_][q_];                             \
            f16 hv_ = (f16)v_;                                                 \
            f16 lv_ = (f16)(v_ - (float)hv_);                                  \
            STW(buf, i_, dl_, q_, hv_, lv_) }

    // ---- stage xh, compute x_part ----
    if (t < QD) xh_s[t] = xh[(size_t)n * QD + t];
    __syncthreads();
    if (t < QD) {
        const float4* wr = (const float4*)(Wp + (size_t)t * (2 * QD));
        const float4* xv = (const float4*)xh_s;
        float acc = 0.f;
        #pragma unroll
        for (int j = 0; j < QD / 4; ++j) {
            float4 a = wr[j], bv = xv[j];
            acc = fmaf(a.x, bv.x, acc);
            acc = fmaf(a.y, bv.y, acc);
            acc = fmaf(a.z, bv.z, acc);
            acc = fmaf(a.w, bv.w, acc);
        }
        xp_s[t] = acc;
    }
    __syncthreads();

    // ---- init C: Cacc[i][d] lane l reg q = C[baserow+i*16+lg*4+q][d*16+ln] ----
    f32x4 Cacc[2][8];
    #pragma unroll
    for (int i = 0; i < 2; ++i)
        #pragma unroll
        for (int d = 0; d < 8; ++d) {
            float xpv = xp_s[d * 16 + ln];
            #pragma unroll
            for (int q = 0; q < 4; ++q)
                Cacc[i][d][q] = xpv +
                    cpart[(size_t)(baserow + i * 16 + lg * 4 + q) * QD + d * 16 + ln];
        }

    // ---- residual blocks ----
    #pragma unroll 1
    for (int b = 0; b < QNBLK; ++b) {
        // per-lane weight base pointers (cid stride 1024B; lane offset l*16B)
        const char* pb1h = ws + WS_W1H + (size_t)b * 65536 + (size_t)l * 16;
        const char* pb1l = ws + WS_W1L + (size_t)b * 65536 + (size_t)l * 16;
        const char* pb2h = ws + WS_W2H + (size_t)b * 65536 + (size_t)l * 16;
        const char* pb2l = ws + WS_W2L + (size_t)b * 65536 + (size_t)l * 16;
        const float* b1row = b1g + (size_t)b * QHID;
        const float* b2row = b2g + (size_t)b * QD;

        // --- A1 staging, pipelined: w0 w1 r0 w2 r1 w3 r2 r3 ---
        f16x8 a1hi[2][4], a1lo[2][4];
        WRC(0, 0)
        WRC(1, 1)
        #pragma unroll
        for (int i = 0; i < 2; ++i) LDF(0, i, a1hi[i][0], a1lo[i][0])
        WRC(2, 0)
        #pragma unroll
        for (int i = 0; i < 2; ++i) LDF(1, i, a1hi[i][1], a1lo[i][1])
        WRC(3, 1)
        #pragma unroll
        for (int i = 0; i < 2; ++i) LDF(0, i, a1hi[i][2], a1lo[i][2])
        #pragma unroll
        for (int i = 0; i < 2; ++i) LDF(1, i, a1hi[i][3], a1lo[i][3])

        // GEMM1 for chunk hc -> H (m=code, n=h32), f16x3
        #define GEMM1(hc) {                                                    \
            float bv0 = b1row[(hc)*32 + ln];                                   \
            float bv1 = b1row[(hc)*32 + 16 + ln];                              \
            H[0][0] = (f32x4){bv0, bv0, bv0, bv0};                             \
            H[1][0] = H[0][0];                                                 \
            H[0][1] = (f32x4){bv1, bv1, bv1, bv1};                             \
            H[1][1] = H[0][1];                                                 \
            const char* q1h = pb1h + (hc)*8192;                                \
            const char* q1l = pb1l + (hc)*8192;                                \
            _Pragma("unroll") for (int kk = 0; kk < 4; ++kk) {                 \
                f16x8 bh0 = *(const f16x8*)(q1h + kk*1024);                    \
                f16x8 bh1 = *(const f16x8*)(q1h + 4096 + kk*1024);             \
                f16x8 bl0 = *(const f16x8*)(q1l + kk*1024);                    \
                f16x8 bl1 = *(const f16x8*)(q1l + 4096 + kk*1024);             \
                H[0][0] = MF(a1hi[0][kk], bh0, H[0][0]);                       \
                H[1][0] = MF(a1hi[1][kk], bh0, H[1][0]);                       \
                H[0][1] = MF(a1hi[0][kk], bh1, H[0][1]);                       \
                H[1][1] = MF(a1hi[1][kk], bh1, H[1][1]);                       \
                H[0][0] = MF(a1lo[0][kk], bh0, H[0][0]);                       \
                H[1][0] = MF(a1lo[1][kk], bh0, H[1][0]);                       \
                H[0][1] = MF(a1lo[0][kk], bh1, H[0][1]);                       \
                H[1][1] = MF(a1lo[1][kk], bh1, H[1][1]);                       \
                H[0][0] = MF(a1hi[0][kk], bl0, H[0][0]);                       \
                H[1][0] = MF(a1hi[1][kk], bl0, H[1][0]);                       \
                H[0][1] = MF(a1hi[0][kk], bl1, H[0][1]);                       \
                H[1][1] = MF(a1hi[1][kk], bl1, H[1][1]);                       \
            } }

        // relu + split H into stage buf
        #define PACKH(buf)                                                     \
            _Pragma("unroll") for (int i_ = 0; i_ < 2; ++i_)                   \
            _Pragma("unroll") for (int cc_ = 0; cc_ < 2; ++cc_)                \
            _Pragma("unroll") for (int q_ = 0; q_ < 4; ++q_) {                 \
                float v_ = fmaxf(H[i_][cc_][q_], 0.f);                         \
                f16 hv_ = (f16)v_;                                             \
                f16 lv_ = (f16)(v_ - (float)hv_);                              \
                STW(buf, i_, cc_, q_, hv_, lv_) }

        // GEMM2 for chunk hc using a2 frags
        #define GEMM2(hc) {                                                    \
            const char* q2h = pb2h + (hc)*8192;                                \
            const char* q2l = pb2l + (hc)*8192;                                \
            _Pragma("unroll") for (int d = 0; d < 8; ++d) {                    \
                const char* bh_p = (d < 4 ? q2h : q2h + 4096) + (d & 3)*1024;  \
                const char* bl_p = (d < 4 ? q2l : q2l + 4096) + (d & 3)*1024;  \
                f16x8 b2h = *(const f16x8*)bh_p;                               \
                f16x8 b2l = *(const f16x8*)bl_p;                               \
                Cacc[0][d] = MF(a2hi[0], b2h, Cacc[0][d]);                     \
                Cacc[1][d] = MF(a2hi[1], b2h, Cacc[1][d]);                     \
                Cacc[0][d] = MF(a2hi[0], b2l, Cacc[0][d]);                     \
                Cacc[1][d] = MF(a2hi[1], b2l, Cacc[1][d]);                     \
                Cacc[0][d] = MF(a2lo[0], b2h, Cacc[0][d]);                     \
                Cacc[1][d] = MF(a2lo[1], b2h, Cacc[1][d]);                     \
            } }

        f32x4 H[2][2];
        f16x8 a2hi[2], a2lo[2];

        // --- pipelined hc loop: write(hc) covered by GEMM2(hc-1)+GEMM1(hc+1) ---
        GEMM1(0)
        PACKH(0)
        #pragma unroll 1
        for (int hc = 1; hc < 8; ++hc) {
            GEMM1(hc)
            PACKH(hc & 1)
            #pragma unroll
            for (int i = 0; i < 2; ++i) LDF((hc - 1) & 1, i, a2hi[i], a2lo[i])
            GEMM2(hc - 1)
        }
        #pragma unroll
        for (int i = 0; i < 2; ++i) LDF(1, i, a2hi[i], a2lo[i])
        GEMM2(7)

        // add b2
        #pragma unroll
        for (int d = 0; d < 8; ++d) {
            float bv = b2row[d * 16 + ln];
            #pragma unroll
            for (int i = 0; i < 2; ++i)
                #pragma unroll
                for (int q = 0; q < 4; ++q)
                    Cacc[i][d][q] += bv;
        }
    } // b

    // ---- distances & argmin ----
    if (t < QD) {
        float xv  = x[(size_t)n * QD + t];
        float xhv = xh[(size_t)n * QD + t];
        r_s[t] = xv - xhv;
    }
    __syncthreads();

    float rv[8];
    #pragma unroll
    for (int d = 0; d < 8; ++d) rv[d] = r_s[d * 16 + ln];

    #pragma unroll
    for (int i = 0; i < 2; ++i)
        #pragma unroll
        for (int q = 0; q < 4; ++q) {
            float pd = 0.f;
            #pragma unroll
            for (int d = 0; d < 8; ++d) {
                float tt = rv[d] - Cacc[i][d][q];
                pd = fmaf(tt, tt, pd);
            }
            pd += __shfl_xor(pd, 1);
            pd += __shfl_xor(pd, 2);
            pd += __shfl_xor(pd, 4);
            pd += __shfl_xor(pd, 8);
            if (ln == 0) {
                int row = baserow + i * 16 + lg * 4 + q;
                red_d[row] = pd;
                red_i[row] = row;
            }
        }
    __syncthreads();

    for (int off = 128; off > 0; off >>= 1) {
        if (t < off) {
            float d2 = red_d[t + off]; int i2 = red_i[t + off];
            float d1 = red_d[t];       int i1 = red_i[t];
            if (d2 < d1 || (d2 == d1 && i2 < i1)) { red_d[t] = d2; red_i[t] = i2; }
        }
        __syncthreads();
    }
    const int code = red_i[0];

    // winner publishes its C row (static acc indexing via predication)
    if (w == (code >> 5) && lg == ((code >> 2) & 3)) {
        const int ci = (code >> 4) & 1, cq = code & 3;
        #pragma unroll
        for (int i = 0; i < 2; ++i)
            if (i == ci)
                #pragma unroll
                for (int q = 0; q < 4; ++q)
                    if (q == cq)
                        #pragma unroll
                        for (int d = 0; d < 8; ++d)
                            csel[d * 16 + ln] = Cacc[i][d][q];
    }
    __syncthreads();

    // ---- outputs ----
    if (t == 0) out[n] = (float)code;
    if (t < QD) {
        float cs  = csel[t];
        float xhv = xh_s[t];
        out[QN + (size_t)n * QD + t]                       = xhv + cs;   // x_hat_new
        out[QN + (size_t)QN * QD + (size_t)n * QD + t]     = r_s[t];     // r
        out[QN + 2 * (size_t)QN * QD + (size_t)n * QD + t] = cs;         // c_sel
    }

    #undef STW
    #undef LDF
    #undef WRC
    #undef GEMM1
    #undef PACKH
    #undef GEMM2
}

// ---------------------------------------------------------------------------
extern "C" void kernel_launch(void* const* d_in, const int* in_sizes, int n_in,
                              void* d_out, int out_size, void* d_ws, size_t ws_size,
                              hipStream_t stream) {
    const float* x   = (const float*)d_in[0];
    const float* xh  = (const float*)d_in[1];
    const float* cb  = (const float*)d_in[2];
    const float* Wp  = (const float*)d_in[3];
    const float* bp  = (const float*)d_in[4];
    const float* W1  = (const float*)d_in[5];
    const float* b1  = (const float*)d_in[6];
    const float* W2  = (const float*)d_in[7];
    const float* b2  = (const float*)d_in[8];
    float* out = (float*)d_out;

    qinco_prep<<<512, 128, 0, stream>>>(cb, Wp, bp, W1, W2, (char*)d_ws);

    (void)hipFuncSetAttribute((const void*)qinco_main,
                              hipFuncAttributeMaxDynamicSharedMemorySize, L_TOTAL);
    qinco_main<<<QN, 512, L_TOTAL, stream>>>(x, xh, Wp, b1, b2,
                                             (const char*)d_ws, out);
}